// Round 6
// baseline (436.221 us; speedup 1.0000x reference)
//
#include <hip/hip_runtime.h>

// HeteroGNN on MI355X. Inputs/weights/output fp32 (per reference); intermediates bf16.
// Round 6: aggregation fused into GEMM staging (no agg materialization in HBM).
//   k_prep : weights -> bf16 WT[n][k];  k_cvt : x_flow/x_host -> bf16 pools
//   kb1/scanB/kb2/kb3 : binned CSR build (unchanged)
//   k_sage G1: h_flow = lrelu([gather-mean(xhb) | xfb] @ WT0_hf^T + b0)  M=200000 (MFMA)
//   k_sage G2: h_host = lrelu([gather-mean(xfb) | xhb] @ WT0_fh^T + b0)  M=20000
//   k_mfma G3: hT = h_host @ W1_hf_l  (transform BEFORE mean)
//   k_final  : g = lrelu(h_flow@W1_r + gather-mean(hT) + b1); out = g@Wout + b_out
//              (agg staged into dead sW LDS region between the two MFMA phases)
// g_host dead in reference -> W1_fh_* unused.

#define N_HOST 20000
#define N_FLOW 200000
#define NEDGE  600000
#define D_IN   64
#define D_H    128
#define D_OUT  32
#define NSEG   (N_FLOW + N_HOST)
#define NBKT_F 196
#define NBKT_H 79
#define NBKT   (NBKT_F + NBKT_H)   // 275
#define NEB    586                 // ceil(1200000/2048)

typedef unsigned short u16;
typedef unsigned int   u32;
typedef short bf16x8 __attribute__((ext_vector_type(8)));
typedef float f32x4  __attribute__((ext_vector_type(4)));

__device__ __forceinline__ float bfh(u16 h) { return __uint_as_float(((u32)h) << 16); }
__device__ __forceinline__ u16 fbh(float f) {
    u32 u = __float_as_uint(f);
    return (u16)((u + 0x7fffu + ((u >> 16) & 1u)) >> 16);   // RNE
}
__device__ __forceinline__ u32 packbf(float x, float y) {
    return (u32)fbh(x) | ((u32)fbh(y) << 16);
}

// ---------------- weight pre-transpose: WT[n][k] bf16 ----------------
__global__ void k_prep(const float* __restrict__ W0_hf_l, const float* __restrict__ W0_hf_r,
                       const float* __restrict__ W0_fh_l, const float* __restrict__ W0_fh_r,
                       const float* __restrict__ W1_l, const float* __restrict__ W1_r,
                       const float* __restrict__ Wout,
                       u16* __restrict__ WT0_hf, u16* __restrict__ WT0_fh,
                       u16* __restrict__ WT1_l, u16* __restrict__ WT1_r,
                       u16* __restrict__ WTo) {
    int b = blockIdx.x, t = threadIdx.x;
    u16 tmp[8];
    if (b < 32) {
        int e = (b & 7) * 2048 + t * 8;
        int n = e >> 7, k0 = e & 127;
        if (b < 8) {
#pragma unroll
            for (int j = 0; j < 8; j++) {
                int k = k0 + j;
                tmp[j] = fbh(k < 64 ? W0_hf_l[k * D_H + n] : W0_hf_r[(k - 64) * D_H + n]);
            }
            *(uint4*)(WT0_hf + n * 128 + k0) = *(uint4*)tmp;
        } else if (b < 16) {
#pragma unroll
            for (int j = 0; j < 8; j++) {
                int k = k0 + j;
                tmp[j] = fbh(k < 64 ? W0_fh_l[k * D_H + n] : W0_fh_r[(k - 64) * D_H + n]);
            }
            *(uint4*)(WT0_fh + n * 128 + k0) = *(uint4*)tmp;
        } else if (b < 24) {
#pragma unroll
            for (int j = 0; j < 8; j++) tmp[j] = fbh(W1_l[(k0 + j) * D_H + n]);
            *(uint4*)(WT1_l + n * 128 + k0) = *(uint4*)tmp;
        } else {
#pragma unroll
            for (int j = 0; j < 8; j++) tmp[j] = fbh(W1_r[(k0 + j) * D_H + n]);
            *(uint4*)(WT1_r + n * 128 + k0) = *(uint4*)tmp;
        }
    } else {
        int e = (b - 32) * 2048 + t * 8;
        int n = e >> 7, k0 = e & 127;
#pragma unroll
        for (int j = 0; j < 8; j++) tmp[j] = fbh(Wout[(k0 + j) * D_OUT + n]);
        *(uint4*)(WTo + n * 128 + k0) = *(uint4*)tmp;
    }
}

// ---------------- x -> bf16 pools ----------------
__global__ void k_cvt(const float* __restrict__ xf, const float* __restrict__ xh,
                      u16* __restrict__ xfb, u16* __restrict__ xhb) {
    int t = blockIdx.x * 256 + threadIdx.x;   // 8 floats per thread
    const int TF = (N_FLOW * D_IN) / 8;       // 1,600,000
    const int TT = TF + (N_HOST * D_IN) / 8;  // 1,760,000
    if (t >= TT) return;
    const float* src; u16* dst; int base;
    if (t < TF) { src = xf; dst = xfb; base = t * 8; }
    else        { src = xh; dst = xhb; base = (t - TF) * 8; }
    float4 f0 = *(const float4*)(src + base);
    float4 f1 = *(const float4*)(src + base + 4);
    uint4 o;
    o.x = packbf(f0.x, f0.y); o.y = packbf(f0.z, f0.w);
    o.z = packbf(f1.x, f1.y); o.w = packbf(f1.z, f1.w);
    *(uint4*)(dst + base) = o;
}

// ---------------- binned CSR build ----------------
__device__ __forceinline__ int bucket_of(int combined_node) {
    return (combined_node < N_FLOW) ? (combined_node >> 10)
                                    : (NBKT_F + ((combined_node - N_FLOW) >> 8));
}

__global__ void kb1(const int* __restrict__ dst_hf, const int* __restrict__ dst_fh,
                    int* __restrict__ bcnt) {
    __shared__ int h[NBKT];
    int t = threadIdx.x;
    for (int j = t; j < NBKT; j += 256) h[j] = 0;
    __syncthreads();
    int base = blockIdx.x * 2048;
#pragma unroll
    for (int i = 0; i < 8; i++) {
        int e = base + t + i * 256;
        if (e < 2 * NEDGE) {
            int bkt = (e < NEDGE) ? (dst_hf[e] >> 10)
                                  : (NBKT_F + (dst_fh[e - NEDGE] >> 8));
            atomicAdd(&h[bkt], 1);
        }
    }
    __syncthreads();
    for (int j = t; j < NBKT; j += 256)
        if (h[j]) atomicAdd(&bcnt[j], h[j]);
}

__global__ void scanB(const int* __restrict__ bcnt, int* __restrict__ ebase) {
    __shared__ int sp[512];
    int t = threadIdx.x;
    int v = (t < NBKT) ? bcnt[t] : 0;
    sp[t] = v;
    __syncthreads();
    for (int d = 1; d < 512; d <<= 1) {
        int x = (t >= d) ? sp[t - d] : 0;
        __syncthreads();
        sp[t] += x;
        __syncthreads();
    }
    if (t < NBKT) ebase[t] = sp[t] - v;   // exclusive
    if (t == NBKT - 1) ebase[NBKT] = sp[t];
}

__global__ void kb2(const int* __restrict__ src_hf, const int* __restrict__ dst_hf,
                    const int* __restrict__ src_fh, const int* __restrict__ dst_fh,
                    const int* __restrict__ ebase, int* __restrict__ bcur,
                    int2* __restrict__ binE) {
    __shared__ int lh[NBKT];
    __shared__ int lb[NBKT];
    int t = threadIdx.x;
    for (int j = t; j < NBKT; j += 256) lh[j] = 0;
    __syncthreads();
    int base = blockIdx.x * 2048;
    int mybkt[8], myrank[8], mysrc[8], mydst[8];
#pragma unroll
    for (int i = 0; i < 8; i++) {
        int e = base + t + i * 256;
        mybkt[i] = -1;
        if (e < 2 * NEDGE) {
            int s, d;
            if (e < NEDGE) { s = src_hf[e]; d = dst_hf[e]; }
            else           { s = src_fh[e - NEDGE]; d = dst_fh[e - NEDGE] + N_FLOW; }
            int bkt = bucket_of(d);
            mybkt[i] = bkt; mysrc[i] = s; mydst[i] = d;
            myrank[i] = atomicAdd(&lh[bkt], 1);
        }
    }
    __syncthreads();
    for (int j = t; j < NBKT; j += 256)
        lb[j] = lh[j] ? atomicAdd(&bcur[j], lh[j]) : 0;
    __syncthreads();
#pragma unroll
    for (int i = 0; i < 8; i++) {
        if (mybkt[i] >= 0) {
            int pos = ebase[mybkt[i]] + lb[mybkt[i]] + myrank[i];
            binE[pos] = make_int2(mysrc[i], mydst[i]);
        }
    }
}

__global__ __launch_bounds__(256) void kb3(const int2* __restrict__ binE,
                                           const int* __restrict__ ebase,
                                           int* __restrict__ off, int* __restrict__ csr) {
    __shared__ int deg[1024];
    __shared__ int ts[256];
    int b = blockIdx.x, t = threadIdx.x;
    int nbase, ncnt;
    if (b < NBKT_F) { nbase = b << 10; ncnt = min(1024, N_FLOW - nbase); }
    else { nbase = N_FLOW + ((b - NBKT_F) << 8); ncnt = min(256, NSEG - nbase); }
    int e0 = ebase[b], e1 = ebase[b + 1];
    for (int i = t; i < 1024; i += 256) deg[i] = 0;
    __syncthreads();
    for (int e = e0 + t; e < e1; e += 256) {
        int2 p = binE[e];
        atomicAdd(&deg[p.y - nbase], 1);
    }
    __syncthreads();
    int loc[4]; int s = 0;
#pragma unroll
    for (int j = 0; j < 4; j++) { loc[j] = s; s += deg[t * 4 + j]; }
    ts[t] = s;
    __syncthreads();
    for (int d = 1; d < 256; d <<= 1) {
        int x = (t >= d) ? ts[t - d] : 0;
        __syncthreads();
        ts[t] += x;
        __syncthreads();
    }
    int base2 = e0 + ts[t] - s;
    int dsave[4];
#pragma unroll
    for (int j = 0; j < 4; j++) dsave[j] = deg[t * 4 + j];
    __syncthreads();
#pragma unroll
    for (int j = 0; j < 4; j++) {
        int idx = t * 4 + j;
        int st = base2 + loc[j];
        deg[idx] = st;
        if (idx < ncnt) off[nbase + idx] = st + dsave[j];   // segment END
    }
    __syncthreads();
    for (int e = e0 + t; e < e1; e += 256) {
        int2 p = binE[e];
        int r = atomicAdd(&deg[p.y - nbase], 1);
        csr[r] = p.x;
    }
}

// ---------------- fused SAGE layer-0 GEMM ----------------
// A[64x128] = [gather-mean(gpool) | dpool row], staged in LDS; B = WT (128x128).
// segbase: 0 for flow destinations, N_FLOW for host destinations.
__global__ __launch_bounds__(256) void k_sage(
    const u16* __restrict__ gpool, const u16* __restrict__ dpool,
    const int* __restrict__ off, const int* __restrict__ csr, int segbase,
    const u16* __restrict__ WT, const float* __restrict__ bias,
    u16* __restrict__ OUT, int M) {
    __shared__ __align__(16) u16 sA[64 * 136];
    __shared__ __align__(16) u16 sW[128 * 136];
    const int t = threadIdx.x;
    const int m0 = blockIdx.x * 64;
#pragma unroll
    for (int i = 0; i < 8; i++) {
        int q = t + i * 256;
        int row = q >> 4, seg = q & 15;
        *(uint4*)(&sW[row * 136 + seg * 8]) = *(const uint4*)(WT + row * 128 + seg * 8);
    }
    // direct half: k in [64,128)
#pragma unroll
    for (int i = 0; i < 2; i++) {
        int q = t + i * 256;
        int r = q >> 3, c = q & 7;
        int row = m0 + r;
        uint4 v = make_uint4(0u, 0u, 0u, 0u);
        if (row < M) v = *(const uint4*)(dpool + row * 64 + c * 8);
        *(uint4*)(&sA[r * 136 + 64 + c * 8]) = v;
    }
    // gather half: k in [0,64) = mean over CSR neighbors
#pragma unroll
    for (int i = 0; i < 2; i++) {
        int q = t + i * 256;
        int r = q >> 3, c = q & 7;
        int row = m0 + r;
        uint4 o = make_uint4(0u, 0u, 0u, 0u);
        if (row < M) {
            int idx = segbase + row;
            int st = (idx == 0) ? 0 : off[idx - 1];
            int en = off[idx];
            float a[8] = {0.f, 0.f, 0.f, 0.f, 0.f, 0.f, 0.f, 0.f};
            for (int e = st; e < en; e++) {
                int s = csr[e];
                uint4 u = *(const uint4*)(gpool + s * 64 + c * 8);
                a[0] += __uint_as_float(u.x << 16);
                a[1] += __uint_as_float(u.x & 0xffff0000u);
                a[2] += __uint_as_float(u.y << 16);
                a[3] += __uint_as_float(u.y & 0xffff0000u);
                a[4] += __uint_as_float(u.z << 16);
                a[5] += __uint_as_float(u.z & 0xffff0000u);
                a[6] += __uint_as_float(u.w << 16);
                a[7] += __uint_as_float(u.w & 0xffff0000u);
            }
            float inv = (en > st) ? 1.f / (float)(en - st) : 0.f;
            o.x = packbf(a[0] * inv, a[1] * inv);
            o.y = packbf(a[2] * inv, a[3] * inv);
            o.z = packbf(a[4] * inv, a[5] * inv);
            o.w = packbf(a[6] * inv, a[7] * inv);
        }
        *(uint4*)(&sA[r * 136 + c * 8]) = o;
    }
    __syncthreads();
    const int w = t >> 6, ln = t & 63, l15 = ln & 15, quad = ln >> 4;
    const u16* pA = sA + (w * 16 + l15) * 136 + quad * 8;
    const u16* pB = sW + l15 * 136 + quad * 8;
    f32x4 acc[8];
#pragma unroll
    for (int tt = 0; tt < 8; tt++) acc[tt] = (f32x4){0.f, 0.f, 0.f, 0.f};
#pragma unroll
    for (int s = 0; s < 4; s++) {
        bf16x8 a = *(const bf16x8*)(pA + s * 32);
#pragma unroll
        for (int tt = 0; tt < 8; tt++) {
            bf16x8 b = *(const bf16x8*)(pB + tt * 2176 + s * 32);
            acc[tt] = __builtin_amdgcn_mfma_f32_16x16x32_bf16(a, b, acc[tt], 0, 0, 0);
        }
    }
#pragma unroll
    for (int tt = 0; tt < 8; tt++) {
        int col = tt * 16 + l15;
        float bv = bias[col];
#pragma unroll
        for (int i = 0; i < 4; i++) {
            int row = m0 + w * 16 + quad * 4 + i;
            if (row < M) {
                float v = acc[tt][i] + bv;
                v = v > 0.f ? v : 0.01f * v;
                OUT[row * D_H + col] = fbh(v);
            }
        }
    }
}

// ---------------- plain MFMA GEMM (G3): A bf16 [M][128] @ WT^T, no bias/relu ----------------
__global__ __launch_bounds__(256) void k_mfma(
    const u16* __restrict__ A, const u16* __restrict__ WT,
    u16* __restrict__ OUT, int M) {
    __shared__ __align__(16) u16 sA[64 * 136];
    __shared__ __align__(16) u16 sW[128 * 136];
    const int t = threadIdx.x;
    const int m0 = blockIdx.x * 64;
#pragma unroll
    for (int i = 0; i < 8; i++) {
        int q = t + i * 256;
        int row = q >> 4, seg = q & 15;
        *(uint4*)(&sW[row * 136 + seg * 8]) = *(const uint4*)(WT + row * 128 + seg * 8);
    }
#pragma unroll
    for (int i = 0; i < 4; i++) {
        int q = t + i * 256;
        int r = q >> 4, seg = q & 15;
        int row = m0 + r;
        uint4 val = make_uint4(0u, 0u, 0u, 0u);
        if (row < M) val = *(const uint4*)(A + row * 128 + seg * 8);
        *(uint4*)(&sA[r * 136 + seg * 8]) = val;
    }
    __syncthreads();
    const int w = t >> 6, ln = t & 63, l15 = ln & 15, quad = ln >> 4;
    const u16* pA = sA + (w * 16 + l15) * 136 + quad * 8;
    const u16* pB = sW + l15 * 136 + quad * 8;
    f32x4 acc[8];
#pragma unroll
    for (int tt = 0; tt < 8; tt++) acc[tt] = (f32x4){0.f, 0.f, 0.f, 0.f};
#pragma unroll
    for (int s = 0; s < 4; s++) {
        bf16x8 a = *(const bf16x8*)(pA + s * 32);
#pragma unroll
        for (int tt = 0; tt < 8; tt++) {
            bf16x8 b = *(const bf16x8*)(pB + tt * 2176 + s * 32);
            acc[tt] = __builtin_amdgcn_mfma_f32_16x16x32_bf16(a, b, acc[tt], 0, 0, 0);
        }
    }
#pragma unroll
    for (int tt = 0; tt < 8; tt++) {
        int col = tt * 16 + l15;
#pragma unroll
        for (int i = 0; i < 4; i++) {
            int row = m0 + w * 16 + quad * 4 + i;
            if (row < M) OUT[row * D_H + col] = fbh(acc[tt][i]);
        }
    }
}

// ---------------- fused final: g=lrelu(A@W1r + mean(hT[nbrs]) + b1); out=g@Wout+bout ----------------
__global__ __launch_bounds__(256) void k_final(
    const u16* __restrict__ A, const u16* __restrict__ WT1r,
    const float* __restrict__ b1, const u16* __restrict__ hT,
    const int* __restrict__ off, const int* __restrict__ csr,
    const u16* __restrict__ WTo, const float* __restrict__ bout,
    float* __restrict__ OUT, int M) {
    __shared__ __align__(16) u16 sA[64 * 136];    // phase1 A tile; later g tile (wave-private rows)
    __shared__ __align__(16) u16 sW[128 * 136];   // phase1 W1r; after phase1: agg tile [64][136]
    u16* sAg = sW;
    const int t = threadIdx.x;
    const int m0 = blockIdx.x * 64;
#pragma unroll
    for (int i = 0; i < 8; i++) {
        int q = t + i * 256;
        int row = q >> 4, seg = q & 15;
        *(uint4*)(&sW[row * 136 + seg * 8]) = *(const uint4*)(WT1r + row * 128 + seg * 8);
    }
#pragma unroll
    for (int i = 0; i < 4; i++) {
        int q = t + i * 256;
        int r = q >> 4, seg = q & 15;
        int row = m0 + r;
        uint4 val = make_uint4(0u, 0u, 0u, 0u);
        if (row < M) val = *(const uint4*)(A + row * D_H + seg * 8);
        *(uint4*)(&sA[r * 136 + seg * 8]) = val;
    }
    __syncthreads();
    const int w = t >> 6, ln = t & 63, l15 = ln & 15, quad = ln >> 4;
    bf16x8 bo[2][4];   // phase-2 B frags from global (L2-resident)
#pragma unroll
    for (int tt = 0; tt < 2; tt++)
#pragma unroll
        for (int s = 0; s < 4; s++)
            bo[tt][s] = *(const bf16x8*)(WTo + (tt * 16 + l15) * 128 + s * 32 + quad * 8);
    const u16* pA = sA + (w * 16 + l15) * 136 + quad * 8;
    const u16* pB = sW + l15 * 136 + quad * 8;
    f32x4 acc[8];
#pragma unroll
    for (int tt = 0; tt < 8; tt++) acc[tt] = (f32x4){0.f, 0.f, 0.f, 0.f};
#pragma unroll
    for (int s = 0; s < 4; s++) {
        bf16x8 a = *(const bf16x8*)(pA + s * 32);
#pragma unroll
        for (int tt = 0; tt < 8; tt++) {
            bf16x8 b = *(const bf16x8*)(pB + tt * 2176 + s * 32);
            acc[tt] = __builtin_amdgcn_mfma_f32_16x16x32_bf16(a, b, acc[tt], 0, 0, 0);
        }
    }
    __syncthreads();   // phase-1 LDS reads done; sW region now dead -> stage agg there
    // gather-mean of hT rows (128d) for this tile's 64 flow nodes
#pragma unroll
    for (int i = 0; i < 4; i++) {
        int q = t + i * 256;
        int r = q >> 4, c = q & 15;
        int row = m0 + r;
        uint4 o = make_uint4(0u, 0u, 0u, 0u);
        if (row < M) {
            int st = (row == 0) ? 0 : off[row - 1];
            int en = off[row];
            float a[8] = {0.f, 0.f, 0.f, 0.f, 0.f, 0.f, 0.f, 0.f};
            for (int e = st; e < en; e++) {
                int s = csr[e];
                uint4 u = *(const uint4*)(hT + s * D_H + c * 8);
                a[0] += __uint_as_float(u.x << 16);
                a[1] += __uint_as_float(u.x & 0xffff0000u);
                a[2] += __uint_as_float(u.y << 16);
                a[3] += __uint_as_float(u.y & 0xffff0000u);
                a[4] += __uint_as_float(u.z << 16);
                a[5] += __uint_as_float(u.z & 0xffff0000u);
                a[6] += __uint_as_float(u.w << 16);
                a[7] += __uint_as_float(u.w & 0xffff0000u);
            }
            float inv = (en > st) ? 1.f / (float)(en - st) : 0.f;
            o.x = packbf(a[0] * inv, a[1] * inv);
            o.y = packbf(a[2] * inv, a[3] * inv);
            o.z = packbf(a[4] * inv, a[5] * inv);
            o.w = packbf(a[6] * inv, a[7] * inv);
        }
        *(uint4*)(&sAg[r * 136 + c * 8]) = o;
    }
    __syncthreads();
    // epilogue: g = lrelu(acc + agg + b1) -> own sA rows (wave-private; per-wave DS in-order)
#pragma unroll
    for (int tt = 0; tt < 8; tt++) {
        int col = tt * 16 + l15;
        float bv = b1[col];
#pragma unroll
        for (int i = 0; i < 4; i++) {
            int rl = w * 16 + quad * 4 + i;
            float ag = bfh(sAg[rl * 136 + col]);
            float v = acc[tt][i] + ag + bv;
            v = v > 0.f ? v : 0.01f * v;
            sA[rl * 136 + col] = fbh(v);
        }
    }
    // phase 2: out = g @ Wout + bout
    f32x4 acc2[2];
    acc2[0] = (f32x4){0.f, 0.f, 0.f, 0.f};
    acc2[1] = (f32x4){0.f, 0.f, 0.f, 0.f};
#pragma unroll
    for (int s = 0; s < 4; s++) {
        bf16x8 g = *(const bf16x8*)(pA + s * 32);
        acc2[0] = __builtin_amdgcn_mfma_f32_16x16x32_bf16(g, bo[0][s], acc2[0], 0, 0, 0);
        acc2[1] = __builtin_amdgcn_mfma_f32_16x16x32_bf16(g, bo[1][s], acc2[1], 0, 0, 0);
    }
#pragma unroll
    for (int tt = 0; tt < 2; tt++) {
        int col = tt * 16 + l15;
        float bv = bout[col];
#pragma unroll
        for (int i = 0; i < 4; i++) {
            int row = m0 + w * 16 + quad * 4 + i;
            if (row < M) OUT[row * D_OUT + col] = acc2[tt][i] + bv;
        }
    }
}

extern "C" void kernel_launch(void* const* d_in, const int* in_sizes, int n_in,
                              void* d_out, int out_size, void* d_ws, size_t ws_size,
                              hipStream_t stream) {
    const float* x_host  = (const float*)d_in[0];
    const float* x_flow  = (const float*)d_in[1];
    const int* src_hf  = (const int*)d_in[2];
    const int* dst_hf  = (const int*)d_in[3];
    const int* src_fh  = (const int*)d_in[4];
    const int* dst_fh  = (const int*)d_in[5];
    const float* W0_hf_l = (const float*)d_in[6];
    const float* W0_hf_r = (const float*)d_in[7];
    const float* b0_hf   = (const float*)d_in[8];
    const float* W0_fh_l = (const float*)d_in[9];
    const float* W0_fh_r = (const float*)d_in[10];
    const float* b0_fh   = (const float*)d_in[11];
    const float* W1_hf_l = (const float*)d_in[12];
    const float* W1_hf_r = (const float*)d_in[13];
    const float* b1_hf   = (const float*)d_in[14];
    const float* W_out   = (const float*)d_in[18];
    const float* b_out   = (const float*)d_in[19];
    float* out = (float*)d_out;

    // workspace layout (bytes), total ~105 MB, all offsets 16B-aligned
    char* ws = (char*)d_ws;
    int*  off    = (int*)(ws + 0);             //   880,000
    int*  csr    = (int*)(ws + 880000);        // 4,800,000
    u16*  h_flow = (u16*)(ws + 5680000);       // 51,200,000
    u16*  hT     = (u16*)(ws + 56880000);      //  5,120,000
    u16*  h_host = (u16*)(ws + 62000000);      //  5,120,000
    u16*  xfb    = (u16*)(ws + 67120000);      // 25,600,000
    u16*  xhb    = (u16*)(ws + 92720000);      //  2,560,000
    int2* binE   = (int2*)(ws + 95280000);     //  9,600,000
    int*  bcnt   = (int*)(ws + 104880000);     //  1,280
    int*  bcur   = (int*)(ws + 104881280);     //  1,280
    int*  ebase  = (int*)(ws + 104882560);     //  1,280
    u16*  WT0_hf = (u16*)(ws + 104883840);     //  32,768
    u16*  WT0_fh = (u16*)(ws + 104916608);     //  32,768
    u16*  WT1_l  = (u16*)(ws + 104949376);     //  32,768
    u16*  WT1_r  = (u16*)(ws + 104982144);     //  32,768
    u16*  WTo    = (u16*)(ws + 105014912);     //   8,192

    hipMemsetAsync(bcnt, 0, 2560, stream);     // bcnt + bcur
    k_prep<<<34, 256, 0, stream>>>(W0_hf_l, W0_hf_r, W0_fh_l, W0_fh_r, W1_hf_l, W1_hf_r,
                                   W_out, WT0_hf, WT0_fh, WT1_l, WT1_r, WTo);
    k_cvt<<<6875, 256, 0, stream>>>(x_flow, x_host, xfb, xhb);
    kb1<<<NEB, 256, 0, stream>>>(dst_hf, dst_fh, bcnt);
    scanB<<<1, 512, 0, stream>>>(bcnt, ebase);
    kb2<<<NEB, 256, 0, stream>>>(src_hf, dst_hf, src_fh, dst_fh, ebase, bcur, binE);
    kb3<<<NBKT, 256, 0, stream>>>(binE, ebase, off, csr);
    k_sage<<<3125, 256, 0, stream>>>(xhb, xfb, off, csr, 0,      WT0_hf, b0_hf, h_flow, N_FLOW);
    k_sage<<<313, 256, 0, stream>>>(xfb, xhb, off, csr, N_FLOW, WT0_fh, b0_fh, h_host, N_HOST);
    k_mfma<<<313, 256, 0, stream>>>(h_host, WT1_l, hT, N_HOST);
    k_final<<<3125, 256, 0, stream>>>(h_flow, WT1_r, b1_hf, hT, off, csr, WTo, b_out, out, N_FLOW);
}

// Round 7
// 401.585 us; speedup vs baseline: 1.0862x; 1.0862x over previous
//
#include <hip/hip_runtime.h>

// HeteroGNN on MI355X. Inputs/weights/output fp32 (per reference); intermediates bf16.
// Round 7: two fused compute kernels, single-barrier structure, weights read from L1/L2:
//   k_prep : weights -> bf16 WT[n][k];  k_cvt : x -> bf16 pools
//   kb1/scanB/kb2/kb3 : binned CSR build (unchanged)
//   k_host : h = lrelu([mean(xfb nbrs)|xhb] @ WT0_fh^T + b0); hT = h @ WT1_l^T   (M=20000)
//   k_mega : h = lrelu([mean(xhb nbrs)|xfb] @ WT0_hf^T + b0);
//            g = lrelu(h @ WT1_r^T + mean(hT nbrs) + b1); out = g @ WTo^T + bout (M=200000)
// h_flow/h_host never reach HBM. g_host dead in reference -> W1_fh_* unused.

#define N_HOST 20000
#define N_FLOW 200000
#define NEDGE  600000
#define D_IN   64
#define D_H    128
#define D_OUT  32
#define NSEG   (N_FLOW + N_HOST)
#define NBKT_F 196
#define NBKT_H 79
#define NBKT   (NBKT_F + NBKT_H)   // 275
#define NEB    586                 // ceil(1200000/2048)

typedef unsigned short u16;
typedef unsigned int   u32;
typedef short bf16x8 __attribute__((ext_vector_type(8)));
typedef float f32x4  __attribute__((ext_vector_type(4)));

__device__ __forceinline__ float bfh(u16 h) { return __uint_as_float(((u32)h) << 16); }
__device__ __forceinline__ u16 fbh(float f) {
    u32 u = __float_as_uint(f);
    return (u16)((u + 0x7fffu + ((u >> 16) & 1u)) >> 16);   // RNE
}
__device__ __forceinline__ u32 packbf(float x, float y) {
    return (u32)fbh(x) | ((u32)fbh(y) << 16);
}
__device__ __forceinline__ void acc8(float* a, uint4 u) {
    a[0] += __uint_as_float(u.x << 16);
    a[1] += __uint_as_float(u.x & 0xffff0000u);
    a[2] += __uint_as_float(u.y << 16);
    a[3] += __uint_as_float(u.y & 0xffff0000u);
    a[4] += __uint_as_float(u.z << 16);
    a[5] += __uint_as_float(u.z & 0xffff0000u);
    a[6] += __uint_as_float(u.w << 16);
    a[7] += __uint_as_float(u.w & 0xffff0000u);
}

// batched gather-mean: 8 bf16 (16B chunk coff, rowstride rs in u16) over csr[st..en)
template <int W>
__device__ __forceinline__ uint4 gather_mean(const u16* __restrict__ pool, int rs, int coff,
                                             const int* __restrict__ csr, int st, int en) {
    float a[8] = {0.f, 0.f, 0.f, 0.f, 0.f, 0.f, 0.f, 0.f};
    for (int e = st; e < en; e += W) {
        uint4 u[W];
#pragma unroll
        for (int j = 0; j < W; j++) u[j] = make_uint4(0u, 0u, 0u, 0u);
#pragma unroll
        for (int j = 0; j < W; j++) {
            if (e + j < en) {
                int n = csr[e + j];
                u[j] = *(const uint4*)(pool + n * rs + coff);
            }
        }
#pragma unroll
        for (int j = 0; j < W; j++) acc8(a, u[j]);
    }
    float inv = (en > st) ? 1.f / (float)(en - st) : 0.f;
    uint4 o;
    o.x = packbf(a[0] * inv, a[1] * inv);
    o.y = packbf(a[2] * inv, a[3] * inv);
    o.z = packbf(a[4] * inv, a[5] * inv);
    o.w = packbf(a[6] * inv, a[7] * inv);
    return o;
}

// ---------------- weight pre-transpose: WT[n][k] bf16 ----------------
__global__ void k_prep(const float* __restrict__ W0_hf_l, const float* __restrict__ W0_hf_r,
                       const float* __restrict__ W0_fh_l, const float* __restrict__ W0_fh_r,
                       const float* __restrict__ W1_l, const float* __restrict__ W1_r,
                       const float* __restrict__ Wout,
                       u16* __restrict__ WT0_hf, u16* __restrict__ WT0_fh,
                       u16* __restrict__ WT1_l, u16* __restrict__ WT1_r,
                       u16* __restrict__ WTo) {
    int b = blockIdx.x, t = threadIdx.x;
    u16 tmp[8];
    if (b < 32) {
        int e = (b & 7) * 2048 + t * 8;
        int n = e >> 7, k0 = e & 127;
        if (b < 8) {
#pragma unroll
            for (int j = 0; j < 8; j++) {
                int k = k0 + j;
                tmp[j] = fbh(k < 64 ? W0_hf_l[k * D_H + n] : W0_hf_r[(k - 64) * D_H + n]);
            }
            *(uint4*)(WT0_hf + n * 128 + k0) = *(uint4*)tmp;
        } else if (b < 16) {
#pragma unroll
            for (int j = 0; j < 8; j++) {
                int k = k0 + j;
                tmp[j] = fbh(k < 64 ? W0_fh_l[k * D_H + n] : W0_fh_r[(k - 64) * D_H + n]);
            }
            *(uint4*)(WT0_fh + n * 128 + k0) = *(uint4*)tmp;
        } else if (b < 24) {
#pragma unroll
            for (int j = 0; j < 8; j++) tmp[j] = fbh(W1_l[(k0 + j) * D_H + n]);
            *(uint4*)(WT1_l + n * 128 + k0) = *(uint4*)tmp;
        } else {
#pragma unroll
            for (int j = 0; j < 8; j++) tmp[j] = fbh(W1_r[(k0 + j) * D_H + n]);
            *(uint4*)(WT1_r + n * 128 + k0) = *(uint4*)tmp;
        }
    } else {
        int e = (b - 32) * 2048 + t * 8;
        int n = e >> 7, k0 = e & 127;
#pragma unroll
        for (int j = 0; j < 8; j++) tmp[j] = fbh(Wout[(k0 + j) * D_OUT + n]);
        *(uint4*)(WTo + n * 128 + k0) = *(uint4*)tmp;
    }
}

// ---------------- x -> bf16 pools ----------------
__global__ void k_cvt(const float* __restrict__ xf, const float* __restrict__ xh,
                      u16* __restrict__ xfb, u16* __restrict__ xhb) {
    int t = blockIdx.x * 256 + threadIdx.x;   // 8 floats per thread
    const int TF = (N_FLOW * D_IN) / 8;       // 1,600,000
    const int TT = TF + (N_HOST * D_IN) / 8;  // 1,760,000
    if (t >= TT) return;
    const float* src; u16* dst; int base;
    if (t < TF) { src = xf; dst = xfb; base = t * 8; }
    else        { src = xh; dst = xhb; base = (t - TF) * 8; }
    float4 f0 = *(const float4*)(src + base);
    float4 f1 = *(const float4*)(src + base + 4);
    uint4 o;
    o.x = packbf(f0.x, f0.y); o.y = packbf(f0.z, f0.w);
    o.z = packbf(f1.x, f1.y); o.w = packbf(f1.z, f1.w);
    *(uint4*)(dst + base) = o;
}

// ---------------- binned CSR build ----------------
__device__ __forceinline__ int bucket_of(int combined_node) {
    return (combined_node < N_FLOW) ? (combined_node >> 10)
                                    : (NBKT_F + ((combined_node - N_FLOW) >> 8));
}

__global__ void kb1(const int* __restrict__ dst_hf, const int* __restrict__ dst_fh,
                    int* __restrict__ bcnt) {
    __shared__ int h[NBKT];
    int t = threadIdx.x;
    for (int j = t; j < NBKT; j += 256) h[j] = 0;
    __syncthreads();
    int base = blockIdx.x * 2048;
#pragma unroll
    for (int i = 0; i < 8; i++) {
        int e = base + t + i * 256;
        if (e < 2 * NEDGE) {
            int bkt = (e < NEDGE) ? (dst_hf[e] >> 10)
                                  : (NBKT_F + (dst_fh[e - NEDGE] >> 8));
            atomicAdd(&h[bkt], 1);
        }
    }
    __syncthreads();
    for (int j = t; j < NBKT; j += 256)
        if (h[j]) atomicAdd(&bcnt[j], h[j]);
}

__global__ void scanB(const int* __restrict__ bcnt, int* __restrict__ ebase) {
    __shared__ int sp[512];
    int t = threadIdx.x;
    int v = (t < NBKT) ? bcnt[t] : 0;
    sp[t] = v;
    __syncthreads();
    for (int d = 1; d < 512; d <<= 1) {
        int x = (t >= d) ? sp[t - d] : 0;
        __syncthreads();
        sp[t] += x;
        __syncthreads();
    }
    if (t < NBKT) ebase[t] = sp[t] - v;   // exclusive
    if (t == NBKT - 1) ebase[NBKT] = sp[t];
}

__global__ void kb2(const int* __restrict__ src_hf, const int* __restrict__ dst_hf,
                    const int* __restrict__ src_fh, const int* __restrict__ dst_fh,
                    const int* __restrict__ ebase, int* __restrict__ bcur,
                    int2* __restrict__ binE) {
    __shared__ int lh[NBKT];
    __shared__ int lb[NBKT];
    int t = threadIdx.x;
    for (int j = t; j < NBKT; j += 256) lh[j] = 0;
    __syncthreads();
    int base = blockIdx.x * 2048;
    int mybkt[8], myrank[8], mysrc[8], mydst[8];
#pragma unroll
    for (int i = 0; i < 8; i++) {
        int e = base + t + i * 256;
        mybkt[i] = -1;
        if (e < 2 * NEDGE) {
            int s, d;
            if (e < NEDGE) { s = src_hf[e]; d = dst_hf[e]; }
            else           { s = src_fh[e - NEDGE]; d = dst_fh[e - NEDGE] + N_FLOW; }
            int bkt = bucket_of(d);
            mybkt[i] = bkt; mysrc[i] = s; mydst[i] = d;
            myrank[i] = atomicAdd(&lh[bkt], 1);
        }
    }
    __syncthreads();
    for (int j = t; j < NBKT; j += 256)
        lb[j] = lh[j] ? atomicAdd(&bcur[j], lh[j]) : 0;
    __syncthreads();
#pragma unroll
    for (int i = 0; i < 8; i++) {
        if (mybkt[i] >= 0) {
            int pos = ebase[mybkt[i]] + lb[mybkt[i]] + myrank[i];
            binE[pos] = make_int2(mysrc[i], mydst[i]);
        }
    }
}

__global__ __launch_bounds__(256) void kb3(const int2* __restrict__ binE,
                                           const int* __restrict__ ebase,
                                           int* __restrict__ off, int* __restrict__ csr) {
    __shared__ int deg[1024];
    __shared__ int ts[256];
    int b = blockIdx.x, t = threadIdx.x;
    int nbase, ncnt;
    if (b < NBKT_F) { nbase = b << 10; ncnt = min(1024, N_FLOW - nbase); }
    else { nbase = N_FLOW + ((b - NBKT_F) << 8); ncnt = min(256, NSEG - nbase); }
    int e0 = ebase[b], e1 = ebase[b + 1];
    for (int i = t; i < 1024; i += 256) deg[i] = 0;
    __syncthreads();
    for (int e = e0 + t; e < e1; e += 256) {
        int2 p = binE[e];
        atomicAdd(&deg[p.y - nbase], 1);
    }
    __syncthreads();
    int loc[4]; int s = 0;
#pragma unroll
    for (int j = 0; j < 4; j++) { loc[j] = s; s += deg[t * 4 + j]; }
    ts[t] = s;
    __syncthreads();
    for (int d = 1; d < 256; d <<= 1) {
        int x = (t >= d) ? ts[t - d] : 0;
        __syncthreads();
        ts[t] += x;
        __syncthreads();
    }
    int base2 = e0 + ts[t] - s;
    int dsave[4];
#pragma unroll
    for (int j = 0; j < 4; j++) dsave[j] = deg[t * 4 + j];
    __syncthreads();
#pragma unroll
    for (int j = 0; j < 4; j++) {
        int idx = t * 4 + j;
        int st = base2 + loc[j];
        deg[idx] = st;
        if (idx < ncnt) off[nbase + idx] = st + dsave[j];   // segment END
    }
    __syncthreads();
    for (int e = e0 + t; e < e1; e += 256) {
        int2 p = binE[e];
        int r = atomicAdd(&deg[p.y - nbase], 1);
        csr[r] = p.x;
    }
}

// ---------------- k_host: G2+G3 fused (M=20000) ----------------
// h = lrelu([mean(xfb nbrs) | xhb] @ WT0_fh^T + b0_fh); hT = h @ WT1_l^T
__global__ __launch_bounds__(256) void k_host(
    const u16* __restrict__ xfb, const u16* __restrict__ xhb,
    const int* __restrict__ off, const int* __restrict__ csr,
    const u16* __restrict__ WT0, const float* __restrict__ b0,
    const u16* __restrict__ WT1l, u16* __restrict__ hT, int M) {
    __shared__ __align__(16) u16 sA[64 * 136];
    const int t = threadIdx.x;
    const int m0 = blockIdx.x * 64;
    // stage: direct half (xhb row) k in [64,128); gather half k in [0,64)
#pragma unroll
    for (int i = 0; i < 2; i++) {
        int q = t + i * 256;
        int r = q >> 3, c = q & 7;
        int row = m0 + r;
        uint4 v = make_uint4(0u, 0u, 0u, 0u);
        if (row < M) v = *(const uint4*)(xhb + row * 64 + c * 8);
        *(uint4*)(&sA[r * 136 + 64 + c * 8]) = v;
    }
#pragma unroll
    for (int i = 0; i < 2; i++) {
        int q = t + i * 256;
        int r = q >> 3, c = q & 7;
        int row = m0 + r;
        uint4 o = make_uint4(0u, 0u, 0u, 0u);
        if (row < M) {
            int sid = N_FLOW + row;
            int st = off[sid - 1];     // sid >= 1 always
            int en = off[sid];
            o = gather_mean<8>(xfb, 64, c * 8, csr, st, en);
        }
        *(uint4*)(&sA[r * 136 + c * 8]) = o;
    }
    __syncthreads();
    const int w = t >> 6, ln = t & 63, l15 = ln & 15, quad = ln >> 4;
    const u16* pA = sA + (w * 16 + l15) * 136 + quad * 8;
    const u16* pB0 = WT0 + l15 * 128 + quad * 8;
    f32x4 acc[8];
#pragma unroll
    for (int tt = 0; tt < 8; tt++) acc[tt] = (f32x4){0.f, 0.f, 0.f, 0.f};
#pragma unroll
    for (int s = 0; s < 4; s++) {
        bf16x8 a = *(const bf16x8*)(pA + s * 32);
#pragma unroll
        for (int tt = 0; tt < 8; tt++) {
            bf16x8 b = *(const bf16x8*)(pB0 + tt * 2048 + s * 32);
            acc[tt] = __builtin_amdgcn_mfma_f32_16x16x32_bf16(a, b, acc[tt], 0, 0, 0);
        }
    }
    // epilogue1: h = lrelu(acc + b0) -> own band (wave-private; per-wave DS in-order)
#pragma unroll
    for (int tt = 0; tt < 8; tt++) {
        int col = tt * 16 + l15;
        float bv = b0[col];
#pragma unroll
        for (int i = 0; i < 4; i++) {
            int rl = w * 16 + quad * 4 + i;
            float v = acc[tt][i] + bv;
            v = v > 0.f ? v : 0.01f * v;
            sA[rl * 136 + col] = fbh(v);
        }
    }
    // phase B: hT = h @ WT1l^T
    const u16* pB1 = WT1l + l15 * 128 + quad * 8;
    f32x4 accB[8];
#pragma unroll
    for (int tt = 0; tt < 8; tt++) accB[tt] = (f32x4){0.f, 0.f, 0.f, 0.f};
#pragma unroll
    for (int s = 0; s < 4; s++) {
        bf16x8 a = *(const bf16x8*)(pA + s * 32);
#pragma unroll
        for (int tt = 0; tt < 8; tt++) {
            bf16x8 b = *(const bf16x8*)(pB1 + tt * 2048 + s * 32);
            accB[tt] = __builtin_amdgcn_mfma_f32_16x16x32_bf16(a, b, accB[tt], 0, 0, 0);
        }
    }
#pragma unroll
    for (int tt = 0; tt < 8; tt++) {
        int col = tt * 16 + l15;
#pragma unroll
        for (int i = 0; i < 4; i++) {
            int row = m0 + w * 16 + quad * 4 + i;
            if (row < M) hT[row * D_H + col] = fbh(accB[tt][i]);
        }
    }
}

// ---------------- k_mega: G1+G4 fused (M=200000, no tail) ----------------
__global__ __launch_bounds__(256) void k_mega(
    const u16* __restrict__ xfb, const u16* __restrict__ xhb,
    const int* __restrict__ off, const int* __restrict__ csr,
    const u16* __restrict__ hT,
    const u16* __restrict__ WT0, const float* __restrict__ b0,
    const u16* __restrict__ WT1r, const float* __restrict__ b1,
    const u16* __restrict__ WTo, const float* __restrict__ bout,
    float* __restrict__ OUT) {
    __shared__ __align__(16) u16 sA[64 * 136];    // A0 tile -> h band -> g band
    __shared__ __align__(16) u16 sAg[64 * 136];   // gathered mean(hT) tile
    const int t = threadIdx.x;
    const int m0 = blockIdx.x * 64;
    // stage A0 direct half: xfb row, k in [64,128)
#pragma unroll
    for (int i = 0; i < 2; i++) {
        int q = t + i * 256;
        int r = q >> 3, c = q & 7;
        int row = m0 + r;
        uint4 v = *(const uint4*)(xfb + row * 64 + c * 8);
        *(uint4*)(&sA[r * 136 + 64 + c * 8]) = v;
    }
    // stage A0 gather half: mean(xhb nbrs), k in [0,64)
#pragma unroll
    for (int i = 0; i < 2; i++) {
        int q = t + i * 256;
        int r = q >> 3, c = q & 7;
        int row = m0 + r;
        int st = (row == 0) ? 0 : off[row - 1];
        int en = off[row];
        uint4 o = gather_mean<4>(xhb, 64, c * 8, csr, st, en);
        *(uint4*)(&sA[r * 136 + c * 8]) = o;
    }
    // stage agg tile: mean(hT nbrs), 128d
#pragma unroll
    for (int i = 0; i < 4; i++) {
        int q = t + i * 256;
        int r = q >> 4, c = q & 15;
        int row = m0 + r;
        int st = (row == 0) ? 0 : off[row - 1];
        int en = off[row];
        uint4 o = gather_mean<4>(hT, 128, c * 8, csr, st, en);
        *(uint4*)(&sAg[r * 136 + c * 8]) = o;
    }
    __syncthreads();   // single barrier
    const int w = t >> 6, ln = t & 63, l15 = ln & 15, quad = ln >> 4;
    const u16* pA = sA + (w * 16 + l15) * 136 + quad * 8;
    const u16* pB0 = WT0 + l15 * 128 + quad * 8;
    f32x4 acc[8];
#pragma unroll
    for (int tt = 0; tt < 8; tt++) acc[tt] = (f32x4){0.f, 0.f, 0.f, 0.f};
#pragma unroll
    for (int s = 0; s < 4; s++) {
        bf16x8 a = *(const bf16x8*)(pA + s * 32);
#pragma unroll
        for (int tt = 0; tt < 8; tt++) {
            bf16x8 b = *(const bf16x8*)(pB0 + tt * 2048 + s * 32);
            acc[tt] = __builtin_amdgcn_mfma_f32_16x16x32_bf16(a, b, acc[tt], 0, 0, 0);
        }
    }
    // epilogue1: h = lrelu(acc + b0) -> own band
#pragma unroll
    for (int tt = 0; tt < 8; tt++) {
        int col = tt * 16 + l15;
        float bv = b0[col];
#pragma unroll
        for (int i = 0; i < 4; i++) {
            int rl = w * 16 + quad * 4 + i;
            float v = acc[tt][i] + bv;
            v = v > 0.f ? v : 0.01f * v;
            sA[rl * 136 + col] = fbh(v);
        }
    }
    // phase B: h @ WT1r^T
    const u16* pB1 = WT1r + l15 * 128 + quad * 8;
    f32x4 accB[8];
#pragma unroll
    for (int tt = 0; tt < 8; tt++) accB[tt] = (f32x4){0.f, 0.f, 0.f, 0.f};
#pragma unroll
    for (int s = 0; s < 4; s++) {
        bf16x8 a = *(const bf16x8*)(pA + s * 32);
#pragma unroll
        for (int tt = 0; tt < 8; tt++) {
            bf16x8 b = *(const bf16x8*)(pB1 + tt * 2048 + s * 32);
            accB[tt] = __builtin_amdgcn_mfma_f32_16x16x32_bf16(a, b, accB[tt], 0, 0, 0);
        }
    }
    // epilogue2: g = lrelu(accB + agg + b1) -> own band
#pragma unroll
    for (int tt = 0; tt < 8; tt++) {
        int col = tt * 16 + l15;
        float bv = b1[col];
#pragma unroll
        for (int i = 0; i < 4; i++) {
            int rl = w * 16 + quad * 4 + i;
            float v = accB[tt][i] + bfh(sAg[rl * 136 + col]) + bv;
            v = v > 0.f ? v : 0.01f * v;
            sA[rl * 136 + col] = fbh(v);
        }
    }
    // phase C: out = g @ WTo^T + bout
    const u16* pBo = WTo + l15 * 128 + quad * 8;
    f32x4 acc2[2];
    acc2[0] = (f32x4){0.f, 0.f, 0.f, 0.f};
    acc2[1] = (f32x4){0.f, 0.f, 0.f, 0.f};
#pragma unroll
    for (int s = 0; s < 4; s++) {
        bf16x8 g = *(const bf16x8*)(pA + s * 32);
        acc2[0] = __builtin_amdgcn_mfma_f32_16x16x32_bf16(g, *(const bf16x8*)(pBo + s * 32), acc2[0], 0, 0, 0);
        acc2[1] = __builtin_amdgcn_mfma_f32_16x16x32_bf16(g, *(const bf16x8*)(pBo + 2048 + s * 32), acc2[1], 0, 0, 0);
    }
#pragma unroll
    for (int tt = 0; tt < 2; tt++) {
        int col = tt * 16 + l15;
        float bv = bout[col];
#pragma unroll
        for (int i = 0; i < 4; i++) {
            int row = m0 + w * 16 + quad * 4 + i;
            OUT[row * D_OUT + col] = acc2[tt][i] + bv;
        }
    }
}

extern "C" void kernel_launch(void* const* d_in, const int* in_sizes, int n_in,
                              void* d_out, int out_size, void* d_ws, size_t ws_size,
                              hipStream_t stream) {
    const float* x_host  = (const float*)d_in[0];
    const float* x_flow  = (const float*)d_in[1];
    const int* src_hf  = (const int*)d_in[2];
    const int* dst_hf  = (const int*)d_in[3];
    const int* src_fh  = (const int*)d_in[4];
    const int* dst_fh  = (const int*)d_in[5];
    const float* W0_hf_l = (const float*)d_in[6];
    const float* W0_hf_r = (const float*)d_in[7];
    const float* b0_hf   = (const float*)d_in[8];
    const float* W0_fh_l = (const float*)d_in[9];
    const float* W0_fh_r = (const float*)d_in[10];
    const float* b0_fh   = (const float*)d_in[11];
    const float* W1_hf_l = (const float*)d_in[12];
    const float* W1_hf_r = (const float*)d_in[13];
    const float* b1_hf   = (const float*)d_in[14];
    const float* W_out   = (const float*)d_in[18];
    const float* b_out   = (const float*)d_in[19];
    float* out = (float*)d_out;

    // workspace layout (bytes), all disjoint, total ~48.7 MB
    char* ws = (char*)d_ws;
    int*  off    = (int*)(ws + 0);             //   880,000
    int*  csr    = (int*)(ws + 880000);        // 4,800,000
    u16*  hT     = (u16*)(ws + 5680000);       //  5,120,000
    u16*  xfb    = (u16*)(ws + 10800000);      // 25,600,000
    u16*  xhb    = (u16*)(ws + 36400000);      //  2,560,000
    int2* binE   = (int2*)(ws + 38960000);     //  9,600,000
    int*  bcnt   = (int*)(ws + 48560000);      //  1,280
    int*  bcur   = (int*)(ws + 48561280);      //  1,280
    int*  ebase  = (int*)(ws + 48562560);      //  1,280
    u16*  WT0_hf = (u16*)(ws + 48563840);      //  32,768
    u16*  WT0_fh = (u16*)(ws + 48596608);      //  32,768
    u16*  WT1_l  = (u16*)(ws + 48629376);      //  32,768
    u16*  WT1_r  = (u16*)(ws + 48662144);      //  32,768
    u16*  WTo    = (u16*)(ws + 48694912);      //   8,192

    hipMemsetAsync(bcnt, 0, 2560, stream);     // bcnt + bcur
    k_prep<<<34, 256, 0, stream>>>(W0_hf_l, W0_hf_r, W0_fh_l, W0_fh_r, W1_hf_l, W1_hf_r,
                                   W_out, WT0_hf, WT0_fh, WT1_l, WT1_r, WTo);
    k_cvt<<<6875, 256, 0, stream>>>(x_flow, x_host, xfb, xhb);
    kb1<<<NEB, 256, 0, stream>>>(dst_hf, dst_fh, bcnt);
    scanB<<<1, 512, 0, stream>>>(bcnt, ebase);
    kb2<<<NEB, 256, 0, stream>>>(src_hf, dst_hf, src_fh, dst_fh, ebase, bcur, binE);
    kb3<<<NBKT, 256, 0, stream>>>(binE, ebase, off, csr);
    k_host<<<313, 256, 0, stream>>>(xfb, xhb, off, csr, WT0_fh, b0_fh, WT1_l, hT, N_HOST);
    k_mega<<<3125, 256, 0, stream>>>(xfb, xhb, off, csr, hT, WT0_hf, b0_hf,
                                     WT1_r, b1_hf, WTo, b_out, out);
}

// Round 8
// 355.187 us; speedup vs baseline: 1.2281x; 1.1306x over previous
//
#include <hip/hip_runtime.h>

// HeteroGNN on MI355X. Inputs/weights/output fp32 (per reference); intermediates bf16.
// Round 8: CSR windows staged in LDS (csr sorted by dst => per-64-row-tile edges are
// contiguous); gather threads read indices from LDS, killing ~14M redundant global
// index loads. Launch count 10 -> 6 (k_prep+k_cvt+kb1 merged; scanB folded into kb2/kb3).
//   k_pre  : weights->bf16 WT[n][k] | x->bf16 pools | bucket histogram
//   kb2    : bin scatter (in-block 275-prefix)  kb3: per-bucket CSR build (in-block prefix)
//   k_host : h=lrelu([mean(xfb nbrs)|xhb]@WT0_fh^T+b0); hT=h@WT1_l^T        (M=20000)
//   k_mega : h=lrelu([mean(xhb nbrs)|xfb]@WT0_hf^T+b0);
//            g=lrelu(h@WT1_r^T+mean(hT nbrs)+b1); out=g@WTo^T+bout          (M=200000)
// g_host dead in reference -> W1_fh_* unused.

#define N_HOST 20000
#define N_FLOW 200000
#define NEDGE  600000
#define D_IN   64
#define D_H    128
#define D_OUT  32
#define NSEG   (N_FLOW + N_HOST)
#define NBKT_F 196
#define NBKT_H 79
#define NBKT   (NBKT_F + NBKT_H)   // 275
#define NEB    586                 // ceil(1200000/2048)

typedef unsigned short u16;
typedef unsigned int   u32;
typedef short bf16x8 __attribute__((ext_vector_type(8)));
typedef float f32x4  __attribute__((ext_vector_type(4)));

__device__ __forceinline__ float bfh(u16 h) { return __uint_as_float(((u32)h) << 16); }
__device__ __forceinline__ u16 fbh(float f) {
    u32 u = __float_as_uint(f);
    return (u16)((u + 0x7fffu + ((u >> 16) & 1u)) >> 16);   // RNE
}
__device__ __forceinline__ u32 packbf(float x, float y) {
    return (u32)fbh(x) | ((u32)fbh(y) << 16);
}
__device__ __forceinline__ void acc8(float* a, uint4 u) {
    a[0] += __uint_as_float(u.x << 16);
    a[1] += __uint_as_float(u.x & 0xffff0000u);
    a[2] += __uint_as_float(u.y << 16);
    a[3] += __uint_as_float(u.y & 0xffff0000u);
    a[4] += __uint_as_float(u.z << 16);
    a[5] += __uint_as_float(u.z & 0xffff0000u);
    a[6] += __uint_as_float(u.w << 16);
    a[7] += __uint_as_float(u.w & 0xffff0000u);
}

// gather-mean of 16B chunks; neighbor indices from LDS window (fit) or global fallback
__device__ __forceinline__ uint4 gmean(const u16* __restrict__ pool, int rs, int coff,
                                       const int* __restrict__ gcsr,
                                       const int* __restrict__ lcsr, int st0, bool fit,
                                       int st, int en) {
    float a[8] = {0.f, 0.f, 0.f, 0.f, 0.f, 0.f, 0.f, 0.f};
    for (int e = st; e < en; e += 4) {
        int n[4];
#pragma unroll
        for (int j = 0; j < 4; j++)
            n[j] = (e + j < en) ? (fit ? lcsr[e + j - st0] : gcsr[e + j]) : -1;
        uint4 u[4];
#pragma unroll
        for (int j = 0; j < 4; j++)
            u[j] = (n[j] >= 0) ? *(const uint4*)(pool + n[j] * rs + coff)
                               : make_uint4(0u, 0u, 0u, 0u);
#pragma unroll
        for (int j = 0; j < 4; j++) acc8(a, u[j]);
    }
    float inv = (en > st) ? 1.f / (float)(en - st) : 0.f;
    uint4 o;
    o.x = packbf(a[0] * inv, a[1] * inv);
    o.y = packbf(a[2] * inv, a[3] * inv);
    o.z = packbf(a[4] * inv, a[5] * inv);
    o.w = packbf(a[6] * inv, a[7] * inv);
    return o;
}

// ---------------- k_pre: weights transpose | x->bf16 | bucket histogram ----------------
__global__ void k_pre(const float* __restrict__ W0_hf_l, const float* __restrict__ W0_hf_r,
                      const float* __restrict__ W0_fh_l, const float* __restrict__ W0_fh_r,
                      const float* __restrict__ W1_l, const float* __restrict__ W1_r,
                      const float* __restrict__ Wout,
                      u16* __restrict__ WT0_hf, u16* __restrict__ WT0_fh,
                      u16* __restrict__ WT1_l, u16* __restrict__ WT1_r,
                      u16* __restrict__ WTo,
                      const float* __restrict__ xf, const float* __restrict__ xh,
                      u16* __restrict__ xfb, u16* __restrict__ xhb,
                      const int* __restrict__ dst_hf, const int* __restrict__ dst_fh,
                      int* __restrict__ bcnt) {
    int b = blockIdx.x, t = threadIdx.x;
    if (b < 34) {
        u16 tmp[8];
        if (b < 32) {
            int e = (b & 7) * 2048 + t * 8;
            int n = e >> 7, k0 = e & 127;
            if (b < 8) {
#pragma unroll
                for (int j = 0; j < 8; j++) {
                    int k = k0 + j;
                    tmp[j] = fbh(k < 64 ? W0_hf_l[k * D_H + n] : W0_hf_r[(k - 64) * D_H + n]);
                }
                *(uint4*)(WT0_hf + n * 128 + k0) = *(uint4*)tmp;
            } else if (b < 16) {
#pragma unroll
                for (int j = 0; j < 8; j++) {
                    int k = k0 + j;
                    tmp[j] = fbh(k < 64 ? W0_fh_l[k * D_H + n] : W0_fh_r[(k - 64) * D_H + n]);
                }
                *(uint4*)(WT0_fh + n * 128 + k0) = *(uint4*)tmp;
            } else if (b < 24) {
#pragma unroll
                for (int j = 0; j < 8; j++) tmp[j] = fbh(W1_l[(k0 + j) * D_H + n]);
                *(uint4*)(WT1_l + n * 128 + k0) = *(uint4*)tmp;
            } else {
#pragma unroll
                for (int j = 0; j < 8; j++) tmp[j] = fbh(W1_r[(k0 + j) * D_H + n]);
                *(uint4*)(WT1_r + n * 128 + k0) = *(uint4*)tmp;
            }
        } else {
            int e = (b - 32) * 2048 + t * 8;
            int n = e >> 7, k0 = e & 127;
#pragma unroll
            for (int j = 0; j < 8; j++) tmp[j] = fbh(Wout[(k0 + j) * D_OUT + n]);
            *(uint4*)(WTo + n * 128 + k0) = *(uint4*)tmp;
        }
    } else if (b < 34 + 6875) {
        int q = (b - 34) * 256 + t;       // 8 floats per thread
        const int TF = (N_FLOW * D_IN) / 8;
        const int TT = TF + (N_HOST * D_IN) / 8;
        if (q >= TT) return;
        const float* src; u16* dst; int base;
        if (q < TF) { src = xf; dst = xfb; base = q * 8; }
        else        { src = xh; dst = xhb; base = (q - TF) * 8; }
        float4 f0 = *(const float4*)(src + base);
        float4 f1 = *(const float4*)(src + base + 4);
        uint4 o;
        o.x = packbf(f0.x, f0.y); o.y = packbf(f0.z, f0.w);
        o.z = packbf(f1.x, f1.y); o.w = packbf(f1.z, f1.w);
        *(uint4*)(dst + base) = o;
    } else {
        __shared__ int h[NBKT];
        for (int j = t; j < NBKT; j += 256) h[j] = 0;
        __syncthreads();
        int base = (b - 34 - 6875) * 2048;
#pragma unroll
        for (int i = 0; i < 8; i++) {
            int e = base + t + i * 256;
            if (e < 2 * NEDGE) {
                int bkt = (e < NEDGE) ? (dst_hf[e] >> 10)
                                      : (NBKT_F + (dst_fh[e - NEDGE] >> 8));
                atomicAdd(&h[bkt], 1);
            }
        }
        __syncthreads();
        for (int j = t; j < NBKT; j += 256)
            if (h[j]) atomicAdd(&bcnt[j], h[j]);
    }
}

// ---------------- kb2: bin scatter (in-block prefix of bcnt) ----------------
__global__ void kb2(const int* __restrict__ src_hf, const int* __restrict__ dst_hf,
                    const int* __restrict__ src_fh, const int* __restrict__ dst_fh,
                    const int* __restrict__ bcnt, int* __restrict__ bcur,
                    int2* __restrict__ binE) {
    __shared__ int sp[512];    // becomes exclusive bucket base
    __shared__ int lh[NBKT];
    __shared__ int lb[NBKT];
    int t = threadIdx.x;
    int o1 = (t < NBKT) ? bcnt[t] : 0;
    int o2 = (t + 256 < NBKT) ? bcnt[t + 256] : 0;
    sp[t] = o1; sp[t + 256] = o2;
    for (int j = t; j < NBKT; j += 256) lh[j] = 0;
    __syncthreads();
    for (int d = 1; d < 512; d <<= 1) {
        int a0 = (t >= d) ? sp[t - d] : 0;
        int a1 = sp[t + 256 - d];
        __syncthreads();
        sp[t] += a0; sp[t + 256] += a1;
        __syncthreads();
    }
    sp[t] -= o1; sp[t + 256] -= o2;   // exclusive
    __syncthreads();
    int base = blockIdx.x * 2048;
    int mybkt[8], myrank[8], mysrc[8], mydst[8];
#pragma unroll
    for (int i = 0; i < 8; i++) {
        int e = base + t + i * 256;
        mybkt[i] = -1;
        if (e < 2 * NEDGE) {
            int s, d;
            if (e < NEDGE) { s = src_hf[e]; d = dst_hf[e]; }
            else           { s = src_fh[e - NEDGE]; d = dst_fh[e - NEDGE] + N_FLOW; }
            int bkt = (d < N_FLOW) ? (d >> 10) : (NBKT_F + ((d - N_FLOW) >> 8));
            mybkt[i] = bkt; mysrc[i] = s; mydst[i] = d;
            myrank[i] = atomicAdd(&lh[bkt], 1);
        }
    }
    __syncthreads();
    for (int j = t; j < NBKT; j += 256)
        lb[j] = lh[j] ? atomicAdd(&bcur[j], lh[j]) : 0;
    __syncthreads();
#pragma unroll
    for (int i = 0; i < 8; i++) {
        if (mybkt[i] >= 0) {
            int pos = sp[mybkt[i]] + lb[mybkt[i]] + myrank[i];
            binE[pos] = make_int2(mysrc[i], mydst[i]);
        }
    }
}

// ---------------- kb3: per-bucket CSR (in-block prefix of bcnt) ----------------
__global__ __launch_bounds__(256) void kb3(const int2* __restrict__ binE,
                                           const int* __restrict__ bcnt,
                                           int* __restrict__ off, int* __restrict__ csr) {
    __shared__ int sp[512];
    __shared__ int deg[1024];
    __shared__ int ts[256];
    int b = blockIdx.x, t = threadIdx.x;
    sp[t] = (t < NBKT) ? bcnt[t] : 0;
    sp[t + 256] = (t + 256 < NBKT) ? bcnt[t + 256] : 0;
    __syncthreads();
    for (int d = 1; d < 512; d <<= 1) {
        int a0 = (t >= d) ? sp[t - d] : 0;
        int a1 = sp[t + 256 - d];
        __syncthreads();
        sp[t] += a0; sp[t + 256] += a1;
        __syncthreads();
    }
    int e0 = (b == 0) ? 0 : sp[b - 1];
    int e1 = sp[b];
    int nbase, ncnt;
    if (b < NBKT_F) { nbase = b << 10; ncnt = min(1024, N_FLOW - nbase); }
    else { nbase = N_FLOW + ((b - NBKT_F) << 8); ncnt = min(256, NSEG - nbase); }
    for (int i = t; i < 1024; i += 256) deg[i] = 0;
    __syncthreads();
    for (int e = e0 + t; e < e1; e += 256) {
        int2 p = binE[e];
        atomicAdd(&deg[p.y - nbase], 1);
    }
    __syncthreads();
    int loc[4]; int s = 0;
#pragma unroll
    for (int j = 0; j < 4; j++) { loc[j] = s; s += deg[t * 4 + j]; }
    ts[t] = s;
    __syncthreads();
    for (int d = 1; d < 256; d <<= 1) {
        int x = (t >= d) ? ts[t - d] : 0;
        __syncthreads();
        ts[t] += x;
        __syncthreads();
    }
    int base2 = e0 + ts[t] - s;
    int dsave[4];
#pragma unroll
    for (int j = 0; j < 4; j++) dsave[j] = deg[t * 4 + j];
    __syncthreads();
#pragma unroll
    for (int j = 0; j < 4; j++) {
        int idx = t * 4 + j;
        int st = base2 + loc[j];
        deg[idx] = st;
        if (idx < ncnt) off[nbase + idx] = st + dsave[j];   // segment END
    }
    __syncthreads();
    for (int e = e0 + t; e < e1; e += 256) {
        int2 p = binE[e];
        int r = atomicAdd(&deg[p.y - nbase], 1);
        csr[r] = p.x;
    }
}

// ---------------- k_host: G2+G3 fused (M=20000) ----------------
__global__ __launch_bounds__(256) void k_host(
    const u16* __restrict__ xfb, const u16* __restrict__ xhb,
    const int* __restrict__ off, const int* __restrict__ csr,
    const u16* __restrict__ WT0, const float* __restrict__ b0,
    const u16* __restrict__ WT1l, u16* __restrict__ hT, int M) {
    __shared__ __align__(16) u16 sA[64 * 136];
    __shared__ int sOff[72];
    __shared__ int sCsr[2560];
    const int t = threadIdx.x;
    const int m0 = blockIdx.x * 64;
    if (t < 65) {
        int idx = N_FLOW + m0 - 1 + t;
        sOff[t] = off[min(idx, NSEG - 1)];
    }
    // direct half: xhb row, k in [64,128)
#pragma unroll
    for (int i = 0; i < 2; i++) {
        int q = t + i * 256;
        int r = q >> 3, c = q & 7;
        int row = m0 + r;
        uint4 v = make_uint4(0u, 0u, 0u, 0u);
        if (row < M) v = *(const uint4*)(xhb + row * 64 + c * 8);
        *(uint4*)(&sA[r * 136 + 64 + c * 8]) = v;
    }
    __syncthreads();
    int st0 = sOff[0];
    int win = sOff[64] - st0;
    bool fit = (win <= 2560);
    if (fit) for (int e = t; e < win; e += 256) sCsr[e] = csr[st0 + e];
    __syncthreads();
    // gather half: mean(xfb nbrs), k in [0,64)
#pragma unroll
    for (int i = 0; i < 2; i++) {
        int q = t + i * 256;
        int r = q >> 3, c = q & 7;
        int row = m0 + r;
        uint4 o = make_uint4(0u, 0u, 0u, 0u);
        if (row < M) o = gmean(xfb, 64, c * 8, csr, sCsr, st0, fit, sOff[r], sOff[r + 1]);
        *(uint4*)(&sA[r * 136 + c * 8]) = o;
    }
    __syncthreads();
    const int w = t >> 6, ln = t & 63, l15 = ln & 15, quad = ln >> 4;
    const u16* pA = sA + (w * 16 + l15) * 136 + quad * 8;
    const u16* pB0 = WT0 + l15 * 128 + quad * 8;
    f32x4 acc[8];
#pragma unroll
    for (int tt = 0; tt < 8; tt++) acc[tt] = (f32x4){0.f, 0.f, 0.f, 0.f};
#pragma unroll
    for (int s = 0; s < 4; s++) {
        bf16x8 a = *(const bf16x8*)(pA + s * 32);
#pragma unroll
        for (int tt = 0; tt < 8; tt++) {
            bf16x8 b = *(const bf16x8*)(pB0 + tt * 2048 + s * 32);
            acc[tt] = __builtin_amdgcn_mfma_f32_16x16x32_bf16(a, b, acc[tt], 0, 0, 0);
        }
    }
#pragma unroll
    for (int tt = 0; tt < 8; tt++) {
        int col = tt * 16 + l15;
        float bv = b0[col];
#pragma unroll
        for (int i = 0; i < 4; i++) {
            int rl = w * 16 + quad * 4 + i;
            float v = acc[tt][i] + bv;
            v = v > 0.f ? v : 0.01f * v;
            sA[rl * 136 + col] = fbh(v);    // wave-private band, per-wave DS in-order
        }
    }
    const u16* pB1 = WT1l + l15 * 128 + quad * 8;
    f32x4 accB[8];
#pragma unroll
    for (int tt = 0; tt < 8; tt++) accB[tt] = (f32x4){0.f, 0.f, 0.f, 0.f};
#pragma unroll
    for (int s = 0; s < 4; s++) {
        bf16x8 a = *(const bf16x8*)(pA + s * 32);
#pragma unroll
        for (int tt = 0; tt < 8; tt++) {
            bf16x8 b = *(const bf16x8*)(pB1 + tt * 2048 + s * 32);
            accB[tt] = __builtin_amdgcn_mfma_f32_16x16x32_bf16(a, b, accB[tt], 0, 0, 0);
        }
    }
#pragma unroll
    for (int tt = 0; tt < 8; tt++) {
        int col = tt * 16 + l15;
#pragma unroll
        for (int i = 0; i < 4; i++) {
            int row = m0 + w * 16 + quad * 4 + i;
            if (row < M) hT[row * D_H + col] = fbh(accB[tt][i]);
        }
    }
}

// ---------------- k_mega: G1+G4 fused (M=200000, no tail) ----------------
__global__ __launch_bounds__(256) void k_mega(
    const u16* __restrict__ xfb, const u16* __restrict__ xhb,
    const int* __restrict__ off, const int* __restrict__ csr,
    const u16* __restrict__ hT,
    const u16* __restrict__ WT0, const float* __restrict__ b0,
    const u16* __restrict__ WT1r, const float* __restrict__ b1,
    const u16* __restrict__ WTo, const float* __restrict__ bout,
    float* __restrict__ OUT) {
    __shared__ __align__(16) u16 sA[64 * 136];    // A0 tile -> h band -> g band
    __shared__ __align__(16) u16 sAg[64 * 136];   // gathered mean(hT) tile
    __shared__ int sOff[72];
    __shared__ int sCsr[1024];
    const int t = threadIdx.x;
    const int m0 = blockIdx.x * 64;
    if (t < 65) {
        int idx = m0 - 1 + t;
        sOff[t] = (idx < 0) ? 0 : off[idx];
    }
    // direct half: xfb row, k in [64,128)
#pragma unroll
    for (int i = 0; i < 2; i++) {
        int q = t + i * 256;
        int r = q >> 3, c = q & 7;
        int row = m0 + r;
        uint4 v = *(const uint4*)(xfb + row * 64 + c * 8);
        *(uint4*)(&sA[r * 136 + 64 + c * 8]) = v;
    }
    __syncthreads();
    int st0 = sOff[0];
    int win = sOff[64] - st0;
    bool fit = (win <= 1024);
    if (fit) for (int e = t; e < win; e += 256) sCsr[e] = csr[st0 + e];
    __syncthreads();
    // A0 gather half: mean(xhb nbrs), k in [0,64)
#pragma unroll
    for (int i = 0; i < 2; i++) {
        int q = t + i * 256;
        int r = q >> 3, c = q & 7;
        uint4 o = gmean(xhb, 64, c * 8, csr, sCsr, st0, fit, sOff[r], sOff[r + 1]);
        *(uint4*)(&sA[r * 136 + c * 8]) = o;
    }
    // agg tile: mean(hT nbrs), 128d
#pragma unroll
    for (int i = 0; i < 4; i++) {
        int q = t + i * 256;
        int r = q >> 4, c = q & 15;
        uint4 o = gmean(hT, 128, c * 8, csr, sCsr, st0, fit, sOff[r], sOff[r + 1]);
        *(uint4*)(&sAg[r * 136 + c * 8]) = o;
    }
    __syncthreads();
    const int w = t >> 6, ln = t & 63, l15 = ln & 15, quad = ln >> 4;
    const u16* pA = sA + (w * 16 + l15) * 136 + quad * 8;
    const u16* pB0 = WT0 + l15 * 128 + quad * 8;
    f32x4 acc[8];
#pragma unroll
    for (int tt = 0; tt < 8; tt++) acc[tt] = (f32x4){0.f, 0.f, 0.f, 0.f};
#pragma unroll
    for (int s = 0; s < 4; s++) {
        bf16x8 a = *(const bf16x8*)(pA + s * 32);
#pragma unroll
        for (int tt = 0; tt < 8; tt++) {
            bf16x8 b = *(const bf16x8*)(pB0 + tt * 2048 + s * 32);
            acc[tt] = __builtin_amdgcn_mfma_f32_16x16x32_bf16(a, b, acc[tt], 0, 0, 0);
        }
    }
    // epilogue1: h = lrelu(acc + b0) -> own band (wave-private, per-wave DS in-order)
#pragma unroll
    for (int tt = 0; tt < 8; tt++) {
        int col = tt * 16 + l15;
        float bv = b0[col];
#pragma unroll
        for (int i = 0; i < 4; i++) {
            int rl = w * 16 + quad * 4 + i;
            float v = acc[tt][i] + bv;
            v = v > 0.f ? v : 0.01f * v;
            sA[rl * 136 + col] = fbh(v);
        }
    }
    // phase B: h @ WT1r^T
    const u16* pB1 = WT1r + l15 * 128 + quad * 8;
    f32x4 accB[8];
#pragma unroll
    for (int tt = 0; tt < 8; tt++) accB[tt] = (f32x4){0.f, 0.f, 0.f, 0.f};
#pragma unroll
    for (int s = 0; s < 4; s++) {
        bf16x8 a = *(const bf16x8*)(pA + s * 32);
#pragma unroll
        for (int tt = 0; tt < 8; tt++) {
            bf16x8 b = *(const bf16x8*)(pB1 + tt * 2048 + s * 32);
            accB[tt] = __builtin_amdgcn_mfma_f32_16x16x32_bf16(a, b, accB[tt], 0, 0, 0);
        }
    }
    // epilogue2: g = lrelu(accB + agg + b1) -> own band
#pragma unroll
    for (int tt = 0; tt < 8; tt++) {
        int col = tt * 16 + l15;
        float bv = b1[col];
#pragma unroll
        for (int i = 0; i < 4; i++) {
            int rl = w * 16 + quad * 4 + i;
            float v = accB[tt][i] + bfh(sAg[rl * 136 + col]) + bv;
            v = v > 0.f ? v : 0.01f * v;
            sA[rl * 136 + col] = fbh(v);
        }
    }
    // phase C: out = g @ WTo^T + bout
    const u16* pBo = WTo + l15 * 128 + quad * 8;
    f32x4 acc2[2];
    acc2[0] = (f32x4){0.f, 0.f, 0.f, 0.f};
    acc2[1] = (f32x4){0.f, 0.f, 0.f, 0.f};
#pragma unroll
    for (int s = 0; s < 4; s++) {
        bf16x8 g = *(const bf16x8*)(pA + s * 32);
        acc2[0] = __builtin_amdgcn_mfma_f32_16x16x32_bf16(g, *(const bf16x8*)(pBo + s * 32), acc2[0], 0, 0, 0);
        acc2[1] = __builtin_amdgcn_mfma_f32_16x16x32_bf16(g, *(const bf16x8*)(pBo + 2048 + s * 32), acc2[1], 0, 0, 0);
    }
#pragma unroll
    for (int tt = 0; tt < 2; tt++) {
        int col = tt * 16 + l15;
        float bv = bout[col];
#pragma unroll
        for (int i = 0; i < 4; i++) {
            int row = m0 + w * 16 + quad * 4 + i;
            OUT[row * D_OUT + col] = acc2[tt][i] + bv;
        }
    }
}

extern "C" void kernel_launch(void* const* d_in, const int* in_sizes, int n_in,
                              void* d_out, int out_size, void* d_ws, size_t ws_size,
                              hipStream_t stream) {
    const float* x_host  = (const float*)d_in[0];
    const float* x_flow  = (const float*)d_in[1];
    const int* src_hf  = (const int*)d_in[2];
    const int* dst_hf  = (const int*)d_in[3];
    const int* src_fh  = (const int*)d_in[4];
    const int* dst_fh  = (const int*)d_in[5];
    const float* W0_hf_l = (const float*)d_in[6];
    const float* W0_hf_r = (const float*)d_in[7];
    const float* b0_hf   = (const float*)d_in[8];
    const float* W0_fh_l = (const float*)d_in[9];
    const float* W0_fh_r = (const float*)d_in[10];
    const float* b0_fh   = (const float*)d_in[11];
    const float* W1_hf_l = (const float*)d_in[12];
    const float* W1_hf_r = (const float*)d_in[13];
    const float* b1_hf   = (const float*)d_in[14];
    const float* W_out   = (const float*)d_in[18];
    const float* b_out   = (const float*)d_in[19];
    float* out = (float*)d_out;

    // workspace layout (bytes), all disjoint, total ~48.7 MB
    char* ws = (char*)d_ws;
    int*  off    = (int*)(ws + 0);             //   880,000
    int*  csr    = (int*)(ws + 880000);        // 4,800,000
    u16*  hT     = (u16*)(ws + 5680000);       //  5,120,000
    u16*  xfb    = (u16*)(ws + 10800000);      // 25,600,000
    u16*  xhb    = (u16*)(ws + 36400000);      //  2,560,000
    int2* binE   = (int2*)(ws + 38960000);     //  9,600,000
    int*  bcnt   = (int*)(ws + 48560000);      //  1,280
    int*  bcur   = (int*)(ws + 48561280);      //  1,280
    u16*  WT0_hf = (u16*)(ws + 48562560);      //  32,768
    u16*  WT0_fh = (u16*)(ws + 48595328);      //  32,768
    u16*  WT1_l  = (u16*)(ws + 48628096);      //  32,768
    u16*  WT1_r  = (u16*)(ws + 48660864);      //  32,768
    u16*  WTo    = (u16*)(ws + 48693632);      //   8,192

    hipMemsetAsync(bcnt, 0, 2560, stream);     // bcnt + bcur
    k_pre<<<34 + 6875 + NEB, 256, 0, stream>>>(
        W0_hf_l, W0_hf_r, W0_fh_l, W0_fh_r, W1_hf_l, W1_hf_r, W_out,
        WT0_hf, WT0_fh, WT1_l, WT1_r, WTo,
        x_flow, x_host, xfb, xhb, dst_hf, dst_fh, bcnt);
    kb2<<<NEB, 256, 0, stream>>>(src_hf, dst_hf, src_fh, dst_fh, bcnt, bcur, binE);
    kb3<<<NBKT, 256, 0, stream>>>(binE, bcnt, off, csr);
    k_host<<<313, 256, 0, stream>>>(xfb, xhb, off, csr, WT0_fh, b0_fh, WT1_l, hT, N_HOST);
    k_mega<<<3125, 256, 0, stream>>>(xfb, xhb, off, csr, hT, WT0_hf, b0_hf,
                                     WT1_r, b1_hf, WTo, b_out, out);
}